// Round 9
// baseline (351.955 us; speedup 1.0000x reference)
//
#include <hip/hip_runtime.h>
#include <stdint.h>
#include <math.h>

#define NALPH 128
#define NEMB  128
#define NST   512
#define BATCH 256
#define TLEN  256
#define FANIN 640   // NEMB + NST

// No host/device-divergent preprocessor control flow (R11 lesson).
#define SDOT4(a, b, c) __builtin_amdgcn_sdot4((a), (b), (c), false)
typedef __attribute__((ext_vector_type(4))) int i32x4;

// ---------------------------------------------------------------------------
// k_prep (896 blocks x 256 thr):
//  [0,256)    G[tok*512+n] = b_in[n] + sum_e emb[tok,e]*W_in[n,e]  (fp32 exact)
//  [256,768)  W_s row-quant: WqT[kg*512+n] (sdot layout) AND MFMA B-frag
//             order WsF[((nt*8+c)*64+lane)*4+d]; Sd[n]=mx/16129
//  [768,896)  W_out row-quant: WoQ[j*128+a] (fallback) AND WoF frag order;
//             So[a]=mx/16129
// Frag formula (dword kd of row r): c=kd>>4, hi=(kd>>2)&3, d=kd&3,
// lane=hi*16+(r&15), tile=r>>4 — hardware-validated bit-exact by R12 (WsF)
// and R15 (WoF).
// SIZES (R16's fatal lesson): WoF = 64 KB (not 32!), WsF = 256 KB.
// ---------------------------------------------------------------------------
__global__ __launch_bounds__(256) void k_prep(
    const float* __restrict__ emb, const float* __restrict__ W_in,
    const float* __restrict__ b_in, const float* __restrict__ W_out,
    float* __restrict__ G, int* __restrict__ WqT, float* __restrict__ Sd,
    int* __restrict__ WoQ, int* __restrict__ WoF, float* __restrict__ So,
    int* __restrict__ WsF)
{
  int bid = blockIdx.x, tid = threadIdx.x;
  if (bid < 256) {
    int idx = bid * 256 + tid;           // tok*512 + n
    int tok = idx >> 9, n = idx & 511;
    const float* er = emb + tok * NEMB;
    const float* wr = W_in + (size_t)n * FANIN;
    float acc = b_in[n];
#pragma unroll 8
    for (int e = 0; e < NEMB; ++e) acc += er[e] * wr[e];
    G[idx] = acc;
  } else if (bid < 768) {
    int n = bid - 256;                   // W_s row
    __shared__ float smax[128];
    float lw[4]; float m = 0.f;
    if (tid < 128) {
      const float* wr = W_in + (size_t)n * FANIN + NEMB + tid * 4;
#pragma unroll
      for (int i = 0; i < 4; ++i) { lw[i] = wr[i]; m = fmaxf(m, fabsf(lw[i])); }
      smax[tid] = m;
    }
    __syncthreads();
    for (int s2 = 64; s2 > 0; s2 >>= 1) {
      if (tid < s2) smax[tid] = fmaxf(smax[tid], smax[tid + s2]);
      __syncthreads();
    }
    float mx = smax[0];
    if (tid < 128) {
      float r = 127.f / mx;
      uint32_t pk = 0;
#pragma unroll
      for (int i = 0; i < 4; ++i) {
        int qv = (int)rintf(lw[i] * r);
        qv = qv < -127 ? -127 : (qv > 127 ? 127 : qv);
        pk |= (uint32_t)(qv & 0xff) << (8 * i);
      }
      WqT[tid * NST + n] = (int)pk;      // sdot layout
      int kd = tid;
      int c = kd >> 4, hi = (kd >> 2) & 3, d = kd & 3;
      int lane = hi * 16 + (n & 15), nt = n >> 4;
      WsF[(((nt * 8 + c) * 64) + lane) * 4 + d] = (int)pk;  // MFMA B-frag
    }
    if (tid == 0) Sd[n] = mx / 16129.0f;
  } else {
    int a = bid - 768;                   // W_out row
    __shared__ float smax[128];
    float lw[4]; float m = 0.f;
    if (tid < 128) {
      const float* wr = W_out + (size_t)a * NST + tid * 4;
#pragma unroll
      for (int i = 0; i < 4; ++i) { lw[i] = wr[i]; m = fmaxf(m, fabsf(lw[i])); }
      smax[tid] = m;
    }
    __syncthreads();
    for (int s2 = 64; s2 > 0; s2 >>= 1) {
      if (tid < s2) smax[tid] = fmaxf(smax[tid], smax[tid + s2]);
      __syncthreads();
    }
    float mx = smax[0];
    if (tid < 128) {
      float r = 127.f / mx;
      uint32_t pk = 0;
#pragma unroll
      for (int i = 0; i < 4; ++i) {
        int qv = (int)rintf(lw[i] * r);
        qv = qv < -127 ? -127 : (qv > 127 ? 127 : qv);
        pk |= (uint32_t)(qv & 0xff) << (8 * i);
      }
      WoQ[tid * 128 + a] = (int)pk;      // fallback layout
      int kd = tid;
      int c = kd >> 4, hi = (kd >> 2) & 3, d = kd & 3;
      int lane = hi * 16 + (a & 15), ta = a >> 4;
      WoF[(((ta * 8 + c) * 64) + lane) * 4 + d] = (int)pk;  // MFMA B-frag
    }
    if (tid == 0) So[a] = mx / 16129.0f;
  }
}

// ---------------------------------------------------------------------------
// k_rec R17 — R16 VERBATIM (hybrid K-split, both halves register-resident).
// R16's failure was a workspace collision (WoF 64KB overlapping WsF), not
// this kernel. 256 blocks x 512 thr (8 waves, 2/SIMD), tid <-> state row n.
//  k in [0,256):   MFMA. Wave wv owns n-tiles q=0..3; Bf[4][4] = 64 dwords,
//                  AGPR residency FREE for MFMA operands (R12-proven).
//                  16 mfma/wave/step -> ~640 cyc/SIMD on the matrix pipe.
//  k in [256,512): sdot4 with wq[64] register weights (~64 sdot + parking
//                  copies ~520 cyc/SIMD on VALU). Pipes overlap (m114).
// LDS traffic is broadcast-only. Merge is lane-local (R13-validated).
// Integer totals identical to R8/R12/R13 -> absmax exactly 0.009765625.
// ---------------------------------------------------------------------------
__global__ __launch_bounds__(512, 1) void k_rec(
    const int* __restrict__ w, const float* __restrict__ G,
    const int* __restrict__ WqT, const int* __restrict__ WsF,
    const float* __restrict__ Sd, signed char* __restrict__ qstates)
{
  __shared__ __align__(16) signed char qs[2][NST];
  int tid  = threadIdx.x;
  int lane = tid & 63, wv = tid >> 6;
  int l15  = lane & 15, hi = lane >> 4;
  int row  = blockIdx.x;

  // sdot weights: row n=tid, k-dwords [64,128) — coalesced loads.
  int wq[64];
#pragma unroll
  for (int m = 0; m < 64; ++m) wq[m] = WqT[(64 + m) * NST + tid];

  // MFMA B-frags, k-chunks c=0..3 (k<256); frag order R12/R13-proven.
  const i32x4* wsf = (const i32x4*)WsF;
  i32x4 Bf[4][4];
#pragma unroll
  for (int q = 0; q < 4; ++q)
#pragma unroll
    for (int c = 0; c < 4; ++c)
      Bf[q][c] = wsf[((size_t)((wv * 4 + q) * 8 + c)) * 64 + lane];

  float dn = Sd[tid];
  const int* wr = w + row * TLEN;
  float g = G[wr[0] * NST + tid];

  qs[0][tid] = 0;
  __syncthreads();

  signed char* qrow = qstates + (size_t)row * TLEN * NST + tid;

  int p = 0;
  for (int t = 0; t < TLEN; ++t) {
    int tok_n = (t < TLEN - 1) ? wr[t + 1] : 0;
    float g_n = G[tok_n * NST + tid];    // prefetch next step's fin

    // --- MFMA half: A chunks c=0..3, bytes [c*64 + hi*16, +16) ---
    i32x4 A[4];
#pragma unroll
    for (int c = 0; c < 4; ++c)
      A[c] = *(const i32x4*)(qs[p] + c * 64 + hi * 16);
    i32x4 acc0 = {0,0,0,0}, acc1 = {0,0,0,0}, acc2 = {0,0,0,0}, acc3 = {0,0,0,0};
#pragma unroll
    for (int c = 0; c < 4; ++c) {
      acc0 = __builtin_amdgcn_mfma_i32_16x16x64_i8(A[c], Bf[0][c], acc0, 0, 0, 0);
      acc1 = __builtin_amdgcn_mfma_i32_16x16x64_i8(A[c], Bf[1][c], acc1, 0, 0, 0);
      acc2 = __builtin_amdgcn_mfma_i32_16x16x64_i8(A[c], Bf[2][c], acc2, 0, 0, 0);
      acc3 = __builtin_amdgcn_mfma_i32_16x16x64_i8(A[c], Bf[3][c], acc3, 0, 0, 0);
    }

    // --- sdot half: k-dwords [64,128), register weights, broadcast state ---
    const int4* sp = (const int4*)qs[p];     // int4 index 16..31 = k>=256
    int a0 = 0, a1 = 0, a2 = 0, a3 = 0;
#pragma unroll
    for (int jj = 0; jj < 16; ++jj) {
      int4 s = sp[16 + jj];
      a0 = SDOT4(wq[4 * jj + 0], s.x, a0);
      a1 = SDOT4(wq[4 * jj + 1], s.y, a1);
      a2 = SDOT4(wq[4 * jj + 2], s.z, a2);
      a3 = SDOT4(wq[4 * jj + 3], s.w, a3);
    }
    int sd = (a0 + a1) + (a2 + a3);

    // --- merge: lane's own n = tid is tile q=hi, reg 0, col l15 ---
    int vm = (hi & 1) ? ((hi & 2) ? acc3[0] : acc1[0])
                      : ((hi & 2) ? acc2[0] : acc0[0]);
    int acc = vm + sd;

    float a = g + (float)acc * dn;
    a = fminf(fmaxf(a, -15.f), 15.f);
    float e = __expf(2.f * a);           // tanh = 1 - 2/(e^(2a)+1)
    float s = fmaf(-2.f, __builtin_amdgcn_rcpf(e + 1.f), 1.f);
    signed char q8 = (signed char)(int)rintf(s * 127.f);
    qrow[(size_t)t * NST] = q8;
    qs[p ^ 1][tid] = q8;
    __syncthreads();
    g = g_n;
    p ^= 1;
  }
}

// ---------------------------------------------------------------------------
// k_out_mfma — proven in R15 (−30 us vs k_out_i8, bit-exact).
// ---------------------------------------------------------------------------
__global__ __launch_bounds__(256) void k_out_mfma(
    const signed char* __restrict__ qstates, const int* __restrict__ WoF,
    const float* __restrict__ So, const float* __restrict__ b_out,
    float* __restrict__ y)
{
  int tid = threadIdx.x;
  int lane = tid & 63, wv = tid >> 6;
  int l15 = lane & 15, hi = lane >> 4;
  size_t bt0 = (size_t)blockIdx.x * 64 + (size_t)wv * 16;

  const signed char* abase = qstates + (bt0 + l15) * NST + hi * 16;
  i32x4 A[8];
#pragma unroll
  for (int c = 0; c < 8; ++c) A[c] = *(const i32x4*)(abase + c * 64);

  const i32x4* wf = (const i32x4*)WoF;
#pragma unroll
  for (int ta = 0; ta < 8; ++ta) {
    const i32x4* bbase = wf + (size_t)ta * 8 * 64 + lane;
    i32x4 acc = {0, 0, 0, 0};
#pragma unroll
    for (int c = 0; c < 8; ++c)
      acc = __builtin_amdgcn_mfma_i32_16x16x64_i8(A[c], bbase[c * 64], acc, 0, 0, 0);
    int a = ta * 16 + l15;
    float s = So[a], b = b_out[a];
    float* yb = y + (bt0 + hi * 4) * 128 + a;
#pragma unroll
    for (int r = 0; r < 4; ++r) yb[(size_t)r * 128] = (float)acc[r] * s + b;
  }
}

// ---------------------------------------------------------------------------
// k_out_i8 — proven fallback, kept compiled for quick revert (not launched).
// ---------------------------------------------------------------------------
__global__ __launch_bounds__(256) void k_out_i8(
    const signed char* __restrict__ qstates, const int* __restrict__ WoQ,
    const float* __restrict__ So, const float* __restrict__ b_out,
    float* __restrict__ y)
{
  __shared__ __align__(16) int sl[32 * 128];   // 16 KB
  int tid = threadIdx.x;
  size_t bt0 = (size_t)blockIdx.x * 32;
  const int4* gp = (const int4*)(qstates + bt0 * NST);
  int4* slp = (int4*)sl;
#pragma unroll
  for (int i = 0; i < 4; ++i) slp[tid + 256 * i] = gp[tid + 256 * i];
  __syncthreads();

  int a0 = tid & 63, gidx = tid >> 6;
  const int* slg = sl + gidx * 8 * 128;
  int acc0[8], acc1[8];
#pragma unroll
  for (int r = 0; r < 8; ++r) { acc0[r] = 0; acc1[r] = 0; }

  for (int j4 = 0; j4 < 32; ++j4) {
    int w00 = WoQ[(4 * j4 + 0) * 128 + a0];
    int w01 = WoQ[(4 * j4 + 0) * 128 + a0 + 64];
    int w10 = WoQ[(4 * j4 + 1) * 128 + a0];
    int w11 = WoQ[(4 * j4 + 1) * 128 + a0 + 64];
    int w20 = WoQ[(4 * j4 + 2) * 128 + a0];
    int w21 = WoQ[(4 * j4 + 2) * 128 + a0 + 64];
    int w30 = WoQ[(4 * j4 + 3) * 128 + a0];
    int w31 = WoQ[(4 * j4 + 3) * 128 + a0 + 64];
#pragma unroll
    for (int r = 0; r < 8; ++r) {
      int4 s = *(const int4*)&slg[r * 128 + 4 * j4];
      acc0[r] = SDOT4(w00, s.x, acc0[r]);
      acc1[r] = SDOT4(w01, s.x, acc1[r]);
      acc0[r] = SDOT4(w10, s.y, acc0[r]);
      acc1[r] = SDOT4(w11, s.y, acc1[r]);
      acc0[r] = SDOT4(w20, s.z, acc0[r]);
      acc1[r] = SDOT4(w21, s.z, acc1[r]);
      acc0[r] = SDOT4(w30, s.w, acc0[r]);
      acc1[r] = SDOT4(w31, s.w, acc1[r]);
    }
  }

  float s0 = So[a0], s1 = So[a0 + 64];
  float b0 = b_out[a0], b1 = b_out[a0 + 64];
#pragma unroll
  for (int r = 0; r < 8; ++r) {
    size_t rowb = (bt0 + gidx * 8 + r) * 128;
    y[rowb + a0]      = (float)acc0[r] * s0 + b0;
    y[rowb + a0 + 64] = (float)acc1[r] * s1 + b1;
  }
}

// ---------------------------------------------------------------------------
extern "C" void kernel_launch(void* const* d_in, const int* in_sizes, int n_in,
                              void* d_out, int out_size, void* d_ws, size_t ws_size,
                              hipStream_t stream) {
  const int*   w     = (const int*)d_in[0];
  const float* emb   = (const float*)d_in[1];
  const float* W_in  = (const float*)d_in[2];
  const float* b_in  = (const float*)d_in[3];
  const float* W_out = (const float*)d_in[4];
  const float* b_out = (const float*)d_in[5];
  float* y = (float*)d_out;

  // Workspace map (R16 lesson: WoF is 64 KB — 128 rows x 512 B):
  //   [0,256K)    G
  //   [256K,512K) WqT
  //   [512K,514K) Sd
  //   [576K,640K) WoQ        (64 KB)
  //   [640K,641K) So
  //   [704K,768K) WoF        (64 KB, frag-order)
  //   [768K,1024K) WsF       (256 KB, frag-order) — ends exactly at qstates
  //   [1024K, +32M) qstates
  char* ws = (char*)d_ws;
  float*       G       = (float*)ws;
  int*         WqT     = (int*)(ws + (256 << 10));
  float*       Sd      = (float*)(ws + (512 << 10));
  int*         WoQ     = (int*)(ws + (576 << 10));
  float*       So      = (float*)(ws + (640 << 10));
  int*         WoF     = (int*)(ws + (704 << 10));
  int*         WsF     = (int*)(ws + (768 << 10));
  signed char* qstates = (signed char*)(ws + (1024 << 10));

  k_prep<<<896, 256, 0, stream>>>(emb, W_in, b_in, W_out, G, WqT, Sd, WoQ, WoF, So, WsF);
  k_rec <<<BATCH, 512, 0, stream>>>(w, G, WqT, WsF, Sd, qstates);
  k_out_mfma<<<BATCH * TLEN / 64, 256, 0, stream>>>(qstates, WoF, So, b_out, y);
}

// Round 11
// 290.091 us; speedup vs baseline: 1.2133x; 1.2133x over previous
//
#include <hip/hip_runtime.h>
#include <stdint.h>
#include <math.h>

#define NALPH 128
#define NEMB  128
#define NST   512
#define BATCH 256
#define TLEN  256
#define FANIN 640   // NEMB + NST

// No host/device-divergent preprocessor control flow (R11 lesson).
#define SDOT4(a, b, c) __builtin_amdgcn_sdot4((a), (b), (c), false)
typedef __attribute__((ext_vector_type(4))) int i32x4;

// LDS-only barrier, race-fixed (R18 lesson): s_barrier alone is NOT a
// compiler memory fence (LLVM models it as IntrNoMem — that's why
// __syncthreads() is fence+barrier+fence). R18 put the "memory" clobber on
// the waitcnt asm only, so next-iteration ds_reads were hoisted between the
// waitcnt and the barrier -> intermittent stale-state reads on replay.
// Fix: ONE asm statement containing both instructions with a "memory"
// clobber — no memory op can cross it in either direction — plus
// sched_barrier(0) after (guide rule #18) for non-memory op motion.
// This still omits the vmcnt(0) drain (the R18 speed win): per-step global
// qstates stores and G prefetch stay in flight across the barrier.
#define BAR_LDS() do {                                            \
    asm volatile("s_waitcnt lgkmcnt(0)\n\ts_barrier" ::: "memory"); \
    __builtin_amdgcn_sched_barrier(0);                            \
  } while (0)

// ---------------------------------------------------------------------------
// k_prep (896 blocks x 256 thr):
//  [0,256)    G[tok*512+n] = b_in[n] + sum_e emb[tok,e]*W_in[n,e]  (fp32 exact)
//  [256,768)  W_s row-quant: WqT[kg*512+n] (k_rec layout); Sd[n]=mx/16129
//  [768,896)  W_out row-quant: WoQ[j*128+a] (fallback) AND MFMA B-frag order
//             WoF[((ta*8+c)*64+lane)*4+d]; So[a]=mx/16129
// Frag formula hardware-validated bit-exact by R12 (WsF) and R15 (WoF).
// ---------------------------------------------------------------------------
__global__ __launch_bounds__(256) void k_prep(
    const float* __restrict__ emb, const float* __restrict__ W_in,
    const float* __restrict__ b_in, const float* __restrict__ W_out,
    float* __restrict__ G, int* __restrict__ WqT, float* __restrict__ Sd,
    int* __restrict__ WoQ, int* __restrict__ WoF, float* __restrict__ So)
{
  int bid = blockIdx.x, tid = threadIdx.x;
  if (bid < 256) {
    int idx = bid * 256 + tid;           // tok*512 + n
    int tok = idx >> 9, n = idx & 511;
    const float* er = emb + tok * NEMB;
    const float* wr = W_in + (size_t)n * FANIN;
    float acc = b_in[n];
#pragma unroll 8
    for (int e = 0; e < NEMB; ++e) acc += er[e] * wr[e];
    G[idx] = acc;
  } else if (bid < 768) {
    int n = bid - 256;                   // W_s row
    __shared__ float smax[128];
    float lw[4]; float m = 0.f;
    if (tid < 128) {
      const float* wr = W_in + (size_t)n * FANIN + NEMB + tid * 4;
#pragma unroll
      for (int i = 0; i < 4; ++i) { lw[i] = wr[i]; m = fmaxf(m, fabsf(lw[i])); }
      smax[tid] = m;
    }
    __syncthreads();
    for (int s2 = 64; s2 > 0; s2 >>= 1) {
      if (tid < s2) smax[tid] = fmaxf(smax[tid], smax[tid + s2]);
      __syncthreads();
    }
    float mx = smax[0];
    if (tid < 128) {
      float r = 127.f / mx;
      uint32_t pk = 0;
#pragma unroll
      for (int i = 0; i < 4; ++i) {
        int qv = (int)rintf(lw[i] * r);
        qv = qv < -127 ? -127 : (qv > 127 ? 127 : qv);
        pk |= (uint32_t)(qv & 0xff) << (8 * i);
      }
      WqT[tid * NST + n] = (int)pk;      // k_rec reads WqT[j*512+n] coalesced
    }
    if (tid == 0) Sd[n] = mx / 16129.0f;
  } else {
    int a = bid - 768;                   // W_out row
    __shared__ float smax[128];
    float lw[4]; float m = 0.f;
    if (tid < 128) {
      const float* wr = W_out + (size_t)a * NST + tid * 4;
#pragma unroll
      for (int i = 0; i < 4; ++i) { lw[i] = wr[i]; m = fmaxf(m, fabsf(lw[i])); }
      smax[tid] = m;
    }
    __syncthreads();
    for (int s2 = 64; s2 > 0; s2 >>= 1) {
      if (tid < s2) smax[tid] = fmaxf(smax[tid], smax[tid + s2]);
      __syncthreads();
    }
    float mx = smax[0];
    if (tid < 128) {
      float r = 127.f / mx;
      uint32_t pk = 0;
#pragma unroll
      for (int i = 0; i < 4; ++i) {
        int qv = (int)rintf(lw[i] * r);
        qv = qv < -127 ? -127 : (qv > 127 ? 127 : qv);
        pk |= (uint32_t)(qv & 0xff) << (8 * i);
      }
      WoQ[tid * 128 + a] = (int)pk;      // fallback layout
      int kd = tid;
      int c = kd >> 4, hi = (kd >> 2) & 3, d = kd & 3;
      int lane = hi * 16 + (a & 15), ta = a >> 4;
      WoF[(((ta * 8 + c) * 64) + lane) * 4 + d] = (int)pk;  // MFMA B-frag
    }
    if (tid == 0) So[a] = mx / 16129.0f;
  }
}

// ---------------------------------------------------------------------------
// k_rec R19 — R18 structure (lgkmcnt-only barrier, 293 us total) with the
// barrier race FIXED: waitcnt+s_barrier fused into one asm-with-memory-
// clobber so next-step ds_reads cannot be scheduled before the barrier.
// Ping-pong hazard analysis: step t reads qs[p], writes qs[p^1], barrier;
// each wave's lgkmcnt(0) publishes its ds_write AND retires its ds_reads
// before its barrier -> no wave can observe a half-written buffer. Global
// qstates stores have no same-kernel reader — safe to leave in flight
// (the R18 speed win, preserved).
// ---------------------------------------------------------------------------
__global__ __launch_bounds__(512, 1) void k_rec(
    const int* __restrict__ w, const float* __restrict__ G,
    const int* __restrict__ WqT, const float* __restrict__ Sd,
    signed char* __restrict__ qstates)
{
  __shared__ __align__(16) signed char qs[2][NST];
  int tid = threadIdx.x;
  int row = blockIdx.x;

  int wq[128];
#pragma unroll
  for (int j = 0; j < 128; ++j) wq[j] = WqT[j * NST + tid];  // coalesced
  float dn = Sd[tid];

  qs[0][tid] = 0;
  __syncthreads();

  const int* wr = w + row * TLEN;
  signed char* qrow = qstates + (size_t)row * TLEN * NST + tid;

  float g = G[wr[0] * NST + tid];
  int p = 0;
  for (int t = 0; t < TLEN; ++t) {
    int tok_n = (t < TLEN - 1) ? wr[t + 1] : 0;
    float g_n = G[tok_n * NST + tid];    // prefetch next step's fin
    const int4* sp = (const int4*)qs[p];
    int a0 = 0, a1 = 0, a2 = 0, a3 = 0;  // 4 independent chains
#pragma unroll
    for (int j = 0; j < 8; ++j) {
      int4 s0 = sp[4 * j + 0];
      int4 s1 = sp[4 * j + 1];
      int4 s2 = sp[4 * j + 2];
      int4 s3 = sp[4 * j + 3];
      a0 = SDOT4(wq[16 * j +  0], s0.x, a0);
      a1 = SDOT4(wq[16 * j +  1], s0.y, a1);
      a2 = SDOT4(wq[16 * j +  2], s0.z, a2);
      a3 = SDOT4(wq[16 * j +  3], s0.w, a3);
      a0 = SDOT4(wq[16 * j +  4], s1.x, a0);
      a1 = SDOT4(wq[16 * j +  5], s1.y, a1);
      a2 = SDOT4(wq[16 * j +  6], s1.z, a2);
      a3 = SDOT4(wq[16 * j +  7], s1.w, a3);
      a0 = SDOT4(wq[16 * j +  8], s2.x, a0);
      a1 = SDOT4(wq[16 * j +  9], s2.y, a1);
      a2 = SDOT4(wq[16 * j + 10], s2.z, a2);
      a3 = SDOT4(wq[16 * j + 11], s2.w, a3);
      a0 = SDOT4(wq[16 * j + 12], s3.x, a0);
      a1 = SDOT4(wq[16 * j + 13], s3.y, a1);
      a2 = SDOT4(wq[16 * j + 14], s3.z, a2);
      a3 = SDOT4(wq[16 * j + 15], s3.w, a3);
    }
    int acc = (a0 + a1) + (a2 + a3);
    float a = g + (float)acc * dn;
    a = fminf(fmaxf(a, -15.f), 15.f);
    float e = __expf(2.f * a);           // tanh = 1 - 2/(e^(2a)+1)
    float s = fmaf(-2.f, __builtin_amdgcn_rcpf(e + 1.f), 1.f);
    signed char q8 = (signed char)(int)rintf(s * 127.f);
    qrow[(size_t)t * NST] = q8;          // fire-and-forget; no vmcnt wait
    qs[p ^ 1][tid] = q8;
    BAR_LDS();                           // fused waitcnt+barrier (race-fixed)
    g = g_n;
    p ^= 1;
  }
}

// ---------------------------------------------------------------------------
// k_out_mfma — proven in R15 (−30 us vs k_out_i8, bit-exact).
// ---------------------------------------------------------------------------
__global__ __launch_bounds__(256) void k_out_mfma(
    const signed char* __restrict__ qstates, const int* __restrict__ WoF,
    const float* __restrict__ So, const float* __restrict__ b_out,
    float* __restrict__ y)
{
  int tid = threadIdx.x;
  int lane = tid & 63, wv = tid >> 6;
  int l15 = lane & 15, hi = lane >> 4;
  size_t bt0 = (size_t)blockIdx.x * 64 + (size_t)wv * 16;

  const signed char* abase = qstates + (bt0 + l15) * NST + hi * 16;
  i32x4 A[8];
#pragma unroll
  for (int c = 0; c < 8; ++c) A[c] = *(const i32x4*)(abase + c * 64);

  const i32x4* wf = (const i32x4*)WoF;
#pragma unroll
  for (int ta = 0; ta < 8; ++ta) {
    const i32x4* bbase = wf + (size_t)ta * 8 * 64 + lane;
    i32x4 acc = {0, 0, 0, 0};
#pragma unroll
    for (int c = 0; c < 8; ++c)
      acc = __builtin_amdgcn_mfma_i32_16x16x64_i8(A[c], bbase[c * 64], acc, 0, 0, 0);
    int a = ta * 16 + l15;
    float s = So[a], b = b_out[a];
    float* yb = y + (bt0 + hi * 4) * 128 + a;
#pragma unroll
    for (int r = 0; r < 4; ++r) yb[(size_t)r * 128] = (float)acc[r] * s + b;
  }
}

// ---------------------------------------------------------------------------
// k_out_i8 — proven fallback, kept compiled for quick revert (not launched).
// ---------------------------------------------------------------------------
__global__ __launch_bounds__(256) void k_out_i8(
    const signed char* __restrict__ qstates, const int* __restrict__ WoQ,
    const float* __restrict__ So, const float* __restrict__ b_out,
    float* __restrict__ y)
{
  __shared__ __align__(16) int sl[32 * 128];   // 16 KB
  int tid = threadIdx.x;
  size_t bt0 = (size_t)blockIdx.x * 32;
  const int4* gp = (const int4*)(qstates + bt0 * NST);
  int4* slp = (int4*)sl;
#pragma unroll
  for (int i = 0; i < 4; ++i) slp[tid + 256 * i] = gp[tid + 256 * i];
  __syncthreads();

  int a0 = tid & 63, gidx = tid >> 6;
  const int* slg = sl + gidx * 8 * 128;
  int acc0[8], acc1[8];
#pragma unroll
  for (int r = 0; r < 8; ++r) { acc0[r] = 0; acc1[r] = 0; }

  for (int j4 = 0; j4 < 32; ++j4) {
    int w00 = WoQ[(4 * j4 + 0) * 128 + a0];
    int w01 = WoQ[(4 * j4 + 0) * 128 + a0 + 64];
    int w10 = WoQ[(4 * j4 + 1) * 128 + a0];
    int w11 = WoQ[(4 * j4 + 1) * 128 + a0 + 64];
    int w20 = WoQ[(4 * j4 + 2) * 128 + a0];
    int w21 = WoQ[(4 * j4 + 2) * 128 + a0 + 64];
    int w30 = WoQ[(4 * j4 + 3) * 128 + a0];
    int w31 = WoQ[(4 * j4 + 3) * 128 + a0 + 64];
#pragma unroll
    for (int r = 0; r < 8; ++r) {
      int4 s = *(const int4*)&slg[r * 128 + 4 * j4];
      acc0[r] = SDOT4(w00, s.x, acc0[r]);
      acc1[r] = SDOT4(w01, s.x, acc1[r]);
      acc0[r] = SDOT4(w10, s.y, acc0[r]);
      acc1[r] = SDOT4(w11, s.y, acc1[r]);
      acc0[r] = SDOT4(w20, s.z, acc0[r]);
      acc1[r] = SDOT4(w21, s.z, acc1[r]);
      acc0[r] = SDOT4(w30, s.w, acc0[r]);
      acc1[r] = SDOT4(w31, s.w, acc1[r]);
    }
  }

  float s0 = So[a0], s1 = So[a0 + 64];
  float b0 = b_out[a0], b1 = b_out[a0 + 64];
#pragma unroll
  for (int r = 0; r < 8; ++r) {
    size_t rowb = (bt0 + gidx * 8 + r) * 128;
    y[rowb + a0]      = (float)acc0[r] * s0 + b0;
    y[rowb + a0 + 64] = (float)acc1[r] * s1 + b1;
  }
}

// ---------------------------------------------------------------------------
extern "C" void kernel_launch(void* const* d_in, const int* in_sizes, int n_in,
                              void* d_out, int out_size, void* d_ws, size_t ws_size,
                              hipStream_t stream) {
  const int*   w     = (const int*)d_in[0];
  const float* emb   = (const float*)d_in[1];
  const float* W_in  = (const float*)d_in[2];
  const float* b_in  = (const float*)d_in[3];
  const float* W_out = (const float*)d_in[4];
  const float* b_out = (const float*)d_in[5];
  float* y = (float*)d_out;

  // Workspace map (R16 lesson: WoF is 64 KB — 128 rows x 512 B):
  //   [0,256K)    G
  //   [256K,512K) WqT
  //   [512K,514K) Sd
  //   [576K,640K) WoQ        (64 KB)
  //   [640K,641K) So
  //   [704K,768K) WoF        (64 KB, frag-order)
  //   [1024K, +32M) qstates
  char* ws = (char*)d_ws;
  float*       G       = (float*)ws;
  int*         WqT     = (int*)(ws + (256 << 10));
  float*       Sd      = (float*)(ws + (512 << 10));
  int*         WoQ     = (int*)(ws + (576 << 10));
  float*       So      = (float*)(ws + (640 << 10));
  int*         WoF     = (int*)(ws + (704 << 10));
  signed char* qstates = (signed char*)(ws + (1024 << 10));

  k_prep<<<896, 256, 0, stream>>>(emb, W_in, b_in, W_out, G, WqT, Sd, WoQ, WoF, So);
  k_rec <<<BATCH, 512, 0, stream>>>(w, G, WqT, Sd, qstates);
  k_out_mfma<<<BATCH * TLEN / 64, 256, 0, stream>>>(qstates, WoF, So, b_out, y);
}

// Round 12
// 267.668 us; speedup vs baseline: 1.3149x; 1.0838x over previous
//
#include <hip/hip_runtime.h>
#include <stdint.h>
#include <math.h>

#define NALPH 128
#define NEMB  128
#define NST   512
#define BATCH 256
#define TLEN  256
#define FANIN 640   // NEMB + NST

// No host/device-divergent preprocessor control flow (R11 lesson).
#define SDOT4(a, b, c) __builtin_amdgcn_sdot4((a), (b), (c), false)
typedef __attribute__((ext_vector_type(4))) int i32x4;

// LDS-only barrier, race-fixed (R18/R19 lessons): ONE asm statement holding
// both s_waitcnt lgkmcnt(0) and s_barrier with a "memory" clobber (s_barrier
// alone is IntrNoMem to LLVM — ds ops would be hoisted across it), plus
// sched_barrier(0) (rule #18). Omits the vmcnt(0) drain: per-step global
// qstates stores / G prefetches stay in flight across the barrier (R18/R19
// speed win, ~16 us).
#define BAR_LDS() do {                                            \
    asm volatile("s_waitcnt lgkmcnt(0)\n\ts_barrier" ::: "memory"); \
    __builtin_amdgcn_sched_barrier(0);                            \
  } while (0)

// ---------------------------------------------------------------------------
// k_prep (896 blocks x 256 thr):
//  [0,256)    G[tok*512+n] = b_in[n] + sum_e emb[tok,e]*W_in[n,e]  (fp32 exact)
//  [256,768)  W_s row-quant: WqT (sdot fallback layout) AND MFMA B-frag order
//             WsF[((nt*8+c)*64+lane)*4+d]; Sd[n]=mx/16129
//  [768,896)  W_out row-quant: WoQ (fallback) AND WoF frag order; So
// Frag formula (dword kd of row r): c=kd>>4, hi=(kd>>2)&3, d=kd&3,
// lane=hi*16+(r&15), tile=r>>4 — HW-validated bit-exact by R12/R15/R17.
// SIZES: WoF = 64 KB, WsF = 256 KB (R16's collision lesson).
// ---------------------------------------------------------------------------
__global__ __launch_bounds__(256) void k_prep(
    const float* __restrict__ emb, const float* __restrict__ W_in,
    const float* __restrict__ b_in, const float* __restrict__ W_out,
    float* __restrict__ G, int* __restrict__ WqT, float* __restrict__ Sd,
    int* __restrict__ WoQ, int* __restrict__ WoF, float* __restrict__ So,
    int* __restrict__ WsF)
{
  int bid = blockIdx.x, tid = threadIdx.x;
  if (bid < 256) {
    int idx = bid * 256 + tid;           // tok*512 + n
    int tok = idx >> 9, n = idx & 511;
    const float* er = emb + tok * NEMB;
    const float* wr = W_in + (size_t)n * FANIN;
    float acc = b_in[n];
#pragma unroll 8
    for (int e = 0; e < NEMB; ++e) acc += er[e] * wr[e];
    G[idx] = acc;
  } else if (bid < 768) {
    int n = bid - 256;                   // W_s row
    __shared__ float smax[128];
    float lw[4]; float m = 0.f;
    if (tid < 128) {
      const float* wr = W_in + (size_t)n * FANIN + NEMB + tid * 4;
#pragma unroll
      for (int i = 0; i < 4; ++i) { lw[i] = wr[i]; m = fmaxf(m, fabsf(lw[i])); }
      smax[tid] = m;
    }
    __syncthreads();
    for (int s2 = 64; s2 > 0; s2 >>= 1) {
      if (tid < s2) smax[tid] = fmaxf(smax[tid], smax[tid + s2]);
      __syncthreads();
    }
    float mx = smax[0];
    if (tid < 128) {
      float r = 127.f / mx;
      uint32_t pk = 0;
#pragma unroll
      for (int i = 0; i < 4; ++i) {
        int qv = (int)rintf(lw[i] * r);
        qv = qv < -127 ? -127 : (qv > 127 ? 127 : qv);
        pk |= (uint32_t)(qv & 0xff) << (8 * i);
      }
      WqT[tid * NST + n] = (int)pk;      // sdot layout (fallback)
      int kd = tid;
      int c = kd >> 4, hi = (kd >> 2) & 3, d = kd & 3;
      int lane = hi * 16 + (n & 15), nt = n >> 4;
      WsF[(((nt * 8 + c) * 64) + lane) * 4 + d] = (int)pk;  // MFMA B-frag
    }
    if (tid == 0) Sd[n] = mx / 16129.0f;
  } else {
    int a = bid - 768;                   // W_out row
    __shared__ float smax[128];
    float lw[4]; float m = 0.f;
    if (tid < 128) {
      const float* wr = W_out + (size_t)a * NST + tid * 4;
#pragma unroll
      for (int i = 0; i < 4; ++i) { lw[i] = wr[i]; m = fmaxf(m, fabsf(lw[i])); }
      smax[tid] = m;
    }
    __syncthreads();
    for (int s2 = 64; s2 > 0; s2 >>= 1) {
      if (tid < s2) smax[tid] = fmaxf(smax[tid], smax[tid + s2]);
      __syncthreads();
    }
    float mx = smax[0];
    if (tid < 128) {
      float r = 127.f / mx;
      uint32_t pk = 0;
#pragma unroll
      for (int i = 0; i < 4; ++i) {
        int qv = (int)rintf(lw[i] * r);
        qv = qv < -127 ? -127 : (qv > 127 ? 127 : qv);
        pk |= (uint32_t)(qv & 0xff) << (8 * i);
      }
      WoQ[tid * 128 + a] = (int)pk;      // fallback layout
      int kd = tid;
      int c = kd >> 4, hi = (kd >> 2) & 3, d = kd & 3;
      int lane = hi * 16 + (a & 15), ta = a >> 4;
      WoF[(((ta * 8 + c) * 64) + lane) * 4 + d] = (int)pk;  // MFMA B-frag
    }
    if (tid == 0) So[a] = mx / 16129.0f;
  }
}

// ---------------------------------------------------------------------------
// k_rec R20 — full-K MFMA engine (R12) + BAR_LDS (R19) + all-lane epilogue
// (R17's lane-local merge). Why this recombination wins over R19's sdot:
//  * sdot engine: 1375 VALU cyc/step (512 sdot + ~512 AGPR copy tax) AND
//    256 broadcast ds_read_b128/CU-step (~700 cyc LDS pipe) -> wall 2150.
//  * MFMA engine: weights AGPR-resident for FREE; matrix pipe 64 mfma/SIMD
//    x ~20.4 cyc = 1306 cyc/step; A-reads only 64 ds_read_b128/CU-step;
//    VALU just the epilogue. R12's extra ~1000 cyc was (a) __syncthreads
//    vmcnt(0) drain with per-step G-prefetch in flight (full HBM latency in
//    the critical path) and (b) 16-lane serialized epilogue — both fixed
//    here by BAR_LDS and the R17 all-64-lane merge (each proven bit-exact).
// 256 blocks x 512 thr. Wave wv owns n-tiles q=0..3 (n = wv*64+q*16+l15),
// Bf[4][8] = 128 dwords. A rows replicated -> D rows replicated -> lane
// (hi,l15) takes acc[q=hi] reg 0 for its own n = tid. Integer sums identical
// to R8/R12/R17 -> absmax exactly 0.009765625.
// ---------------------------------------------------------------------------
__global__ __launch_bounds__(512, 1) void k_rec(
    const int* __restrict__ w, const float* __restrict__ G,
    const int* __restrict__ WsF, const float* __restrict__ Sd,
    signed char* __restrict__ qstates)
{
  __shared__ __align__(16) signed char qs[2][NST];
  int tid  = threadIdx.x;
  int lane = tid & 63, wv = tid >> 6;
  int l15  = lane & 15, hi = lane >> 4;
  int row  = blockIdx.x;

  // B-fragments: 4 n-tiles x 8 k-chunks (full K), 16B/lane, coalesced.
  const i32x4* wsf = (const i32x4*)WsF;
  i32x4 Bf[4][8];
#pragma unroll
  for (int q = 0; q < 4; ++q)
#pragma unroll
    for (int c = 0; c < 8; ++c)
      Bf[q][c] = wsf[((size_t)((wv * 4 + q) * 8 + c)) * 64 + lane];

  float dn = Sd[tid];
  const int* wr = w + row * TLEN;
  float g = G[wr[0] * NST + tid];

  qs[0][tid] = 0;
  __syncthreads();

  signed char* qrow = qstates + (size_t)row * TLEN * NST + tid;

  int p = 0;
  for (int t = 0; t < TLEN; ++t) {
    int tok_n = (t < TLEN - 1) ? wr[t + 1] : 0;
    float g_n = G[tok_n * NST + tid];    // prefetch; stays in flight past BAR

    // A-fragments: chunk c -> state bytes [c*64 + hi*16, +16). Within a
    // wave, the 16 lanes of each hi-group read the same address (broadcast).
    i32x4 A[8];
#pragma unroll
    for (int c = 0; c < 8; ++c)
      A[c] = *(const i32x4*)(qs[p] + c * 64 + hi * 16);

    i32x4 acc0 = {0,0,0,0}, acc1 = {0,0,0,0}, acc2 = {0,0,0,0}, acc3 = {0,0,0,0};
#pragma unroll
    for (int c = 0; c < 8; ++c) {
      acc0 = __builtin_amdgcn_mfma_i32_16x16x64_i8(A[c], Bf[0][c], acc0, 0, 0, 0);
      acc1 = __builtin_amdgcn_mfma_i32_16x16x64_i8(A[c], Bf[1][c], acc1, 0, 0, 0);
      acc2 = __builtin_amdgcn_mfma_i32_16x16x64_i8(A[c], Bf[2][c], acc2, 0, 0, 0);
      acc3 = __builtin_amdgcn_mfma_i32_16x16x64_i8(A[c], Bf[3][c], acc3, 0, 0, 0);
    }

    // Merge: lane's own n = tid is tile q=hi, reg 0, col l15 (rows
    // replicated). 3-cndmask select, no cross-lane traffic (R17-proven).
    int vm = (hi & 1) ? ((hi & 2) ? acc3[0] : acc1[0])
                      : ((hi & 2) ? acc2[0] : acc0[0]);

    float a = g + (float)vm * dn;
    a = fminf(fmaxf(a, -15.f), 15.f);
    float e = __expf(2.f * a);           // tanh = 1 - 2/(e^(2a)+1)
    float s = fmaf(-2.f, __builtin_amdgcn_rcpf(e + 1.f), 1.f);
    signed char q8 = (signed char)(int)rintf(s * 127.f);
    qrow[(size_t)t * NST] = q8;          // fire-and-forget; no vmcnt wait
    qs[p ^ 1][tid] = q8;
    BAR_LDS();                           // fused waitcnt+barrier (race-fixed)
    g = g_n;
    p ^= 1;
  }
}

// ---------------------------------------------------------------------------
// k_out_mfma — proven in R15 (−30 us vs k_out_i8, bit-exact).
// ---------------------------------------------------------------------------
__global__ __launch_bounds__(256) void k_out_mfma(
    const signed char* __restrict__ qstates, const int* __restrict__ WoF,
    const float* __restrict__ So, const float* __restrict__ b_out,
    float* __restrict__ y)
{
  int tid = threadIdx.x;
  int lane = tid & 63, wv = tid >> 6;
  int l15 = lane & 15, hi = lane >> 4;
  size_t bt0 = (size_t)blockIdx.x * 64 + (size_t)wv * 16;

  const signed char* abase = qstates + (bt0 + l15) * NST + hi * 16;
  i32x4 A[8];
#pragma unroll
  for (int c = 0; c < 8; ++c) A[c] = *(const i32x4*)(abase + c * 64);

  const i32x4* wf = (const i32x4*)WoF;
#pragma unroll
  for (int ta = 0; ta < 8; ++ta) {
    const i32x4* bbase = wf + (size_t)ta * 8 * 64 + lane;
    i32x4 acc = {0, 0, 0, 0};
#pragma unroll
    for (int c = 0; c < 8; ++c)
      acc = __builtin_amdgcn_mfma_i32_16x16x64_i8(A[c], bbase[c * 64], acc, 0, 0, 0);
    int a = ta * 16 + l15;
    float s = So[a], b = b_out[a];
    float* yb = y + (bt0 + hi * 4) * 128 + a;
#pragma unroll
    for (int r = 0; r < 4; ++r) yb[(size_t)r * 128] = (float)acc[r] * s + b;
  }
}

// ---------------------------------------------------------------------------
// k_out_i8 — proven fallback, kept compiled for quick revert (not launched).
// ---------------------------------------------------------------------------
__global__ __launch_bounds__(256) void k_out_i8(
    const signed char* __restrict__ qstates, const int* __restrict__ WoQ,
    const float* __restrict__ So, const float* __restrict__ b_out,
    float* __restrict__ y)
{
  __shared__ __align__(16) int sl[32 * 128];   // 16 KB
  int tid = threadIdx.x;
  size_t bt0 = (size_t)blockIdx.x * 32;
  const int4* gp = (const int4*)(qstates + bt0 * NST);
  int4* slp = (int4*)sl;
#pragma unroll
  for (int i = 0; i < 4; ++i) slp[tid + 256 * i] = gp[tid + 256 * i];
  __syncthreads();

  int a0 = tid & 63, gidx = tid >> 6;
  const int* slg = sl + gidx * 8 * 128;
  int acc0[8], acc1[8];
#pragma unroll
  for (int r = 0; r < 8; ++r) { acc0[r] = 0; acc1[r] = 0; }

  for (int j4 = 0; j4 < 32; ++j4) {
    int w00 = WoQ[(4 * j4 + 0) * 128 + a0];
    int w01 = WoQ[(4 * j4 + 0) * 128 + a0 + 64];
    int w10 = WoQ[(4 * j4 + 1) * 128 + a0];
    int w11 = WoQ[(4 * j4 + 1) * 128 + a0 + 64];
    int w20 = WoQ[(4 * j4 + 2) * 128 + a0];
    int w21 = WoQ[(4 * j4 + 2) * 128 + a0 + 64];
    int w30 = WoQ[(4 * j4 + 3) * 128 + a0];
    int w31 = WoQ[(4 * j4 + 3) * 128 + a0 + 64];
#pragma unroll
    for (int r = 0; r < 8; ++r) {
      int4 s = *(const int4*)&slg[r * 128 + 4 * j4];
      acc0[r] = SDOT4(w00, s.x, acc0[r]);
      acc1[r] = SDOT4(w01, s.x, acc1[r]);
      acc0[r] = SDOT4(w10, s.y, acc0[r]);
      acc1[r] = SDOT4(w11, s.y, acc1[r]);
      acc0[r] = SDOT4(w20, s.z, acc0[r]);
      acc1[r] = SDOT4(w21, s.z, acc1[r]);
      acc0[r] = SDOT4(w30, s.w, acc0[r]);
      acc1[r] = SDOT4(w31, s.w, acc1[r]);
    }
  }

  float s0 = So[a0], s1 = So[a0 + 64];
  float b0 = b_out[a0], b1 = b_out[a0 + 64];
#pragma unroll
  for (int r = 0; r < 8; ++r) {
    size_t rowb = (bt0 + gidx * 8 + r) * 128;
    y[rowb + a0]      = (float)acc0[r] * s0 + b0;
    y[rowb + a0 + 64] = (float)acc1[r] * s1 + b1;
  }
}

// ---------------------------------------------------------------------------
extern "C" void kernel_launch(void* const* d_in, const int* in_sizes, int n_in,
                              void* d_out, int out_size, void* d_ws, size_t ws_size,
                              hipStream_t stream) {
  const int*   w     = (const int*)d_in[0];
  const float* emb   = (const float*)d_in[1];
  const float* W_in  = (const float*)d_in[2];
  const float* b_in  = (const float*)d_in[3];
  const float* W_out = (const float*)d_in[4];
  const float* b_out = (const float*)d_in[5];
  float* y = (float*)d_out;

  // Workspace map (R16 lesson: WoF is 64 KB — 128 rows x 512 B):
  //   [0,256K)     G
  //   [256K,512K)  WqT
  //   [512K,514K)  Sd
  //   [576K,640K)  WoQ   (64 KB)
  //   [640K,641K)  So
  //   [704K,768K)  WoF   (64 KB, frag-order)
  //   [768K,1024K) WsF   (256 KB, frag-order) — ends exactly at qstates
  //   [1024K,+32M) qstates
  char* ws = (char*)d_ws;
  float*       G       = (float*)ws;
  int*         WqT     = (int*)(ws + (256 << 10));
  float*       Sd      = (float*)(ws + (512 << 10));
  int*         WoQ     = (int*)(ws + (576 << 10));
  float*       So      = (float*)(ws + (640 << 10));
  int*         WoF     = (int*)(ws + (704 << 10));
  int*         WsF     = (int*)(ws + (768 << 10));
  signed char* qstates = (signed char*)(ws + (1024 << 10));

  k_prep<<<896, 256, 0, stream>>>(emb, W_in, b_in, W_out, G, WqT, Sd, WoQ, WoF, So, WsF);
  k_rec <<<BATCH, 512, 0, stream>>>(w, G, WsF, Sd, qstates);
  k_out_mfma<<<BATCH * TLEN / 64, 256, 0, stream>>>(qstates, WoF, So, b_out, y);
}

// Round 13
// 266.406 us; speedup vs baseline: 1.3211x; 1.0047x over previous
//
#include <hip/hip_runtime.h>
#include <stdint.h>
#include <math.h>

#define NALPH 128
#define NEMB  128
#define NST   512
#define BATCH 256
#define TLEN  256
#define FANIN 640   // NEMB + NST

// No host/device-divergent preprocessor control flow (R11 lesson).
#define SDOT4(a, b, c) __builtin_amdgcn_sdot4((a), (b), (c), false)
typedef __attribute__((ext_vector_type(4))) int i32x4;

// LDS-only barrier, race-fixed (R18/R19 lessons): ONE asm statement holding
// both s_waitcnt lgkmcnt(0) and s_barrier with a "memory" clobber (s_barrier
// alone is IntrNoMem to LLVM — ds ops would be hoisted across it), plus
// sched_barrier(0) (rule #18). Omits the vmcnt(0) drain: per-step global
// qstates stores / G prefetches stay in flight across the barrier.
#define BAR_LDS() do {                                            \
    asm volatile("s_waitcnt lgkmcnt(0)\n\ts_barrier" ::: "memory"); \
    __builtin_amdgcn_sched_barrier(0);                            \
  } while (0)

// ---------------------------------------------------------------------------
// k_prep (896 blocks x 256 thr):
//  [0,256)    G[tok*512+n] = b_in[n] + sum_e emb[tok,e]*W_in[n,e]  (fp32 exact)
//             R21: float4-vectorized loads (was scalar: stride-2560B across
//             lanes = 64 lines/instr x 128 iters, ~50 us). Same e-order +
//             explicit fmaf -> G bit-identical to the scalar version.
//  [256,768)  W_s row-quant: WqT (sdot fallback) AND WsF MFMA B-frag; Sd
//  [768,896)  W_out row-quant: WoQ (fallback) AND WoF frag order; So
// Frag formula (dword kd of row r): c=kd>>4, hi=(kd>>2)&3, d=kd&3,
// lane=hi*16+(r&15), tile=r>>4 — HW-validated bit-exact by R12/R15/R17/R20.
// SIZES: WoF = 64 KB, WsF = 256 KB (R16's collision lesson).
// ---------------------------------------------------------------------------
__global__ __launch_bounds__(256) void k_prep(
    const float* __restrict__ emb, const float* __restrict__ W_in,
    const float* __restrict__ b_in, const float* __restrict__ W_out,
    float* __restrict__ G, int* __restrict__ WqT, float* __restrict__ Sd,
    int* __restrict__ WoQ, int* __restrict__ WoF, float* __restrict__ So,
    int* __restrict__ WsF)
{
  int bid = blockIdx.x, tid = threadIdx.x;
  if (bid < 256) {
    int idx = bid * 256 + tid;           // tok*512 + n
    int tok = idx >> 9, n = idx & 511;
    const float4* er = (const float4*)(emb + tok * NEMB);          // 16B-aligned
    const float4* wr = (const float4*)(W_in + (size_t)n * FANIN);  // 2560B rows
    float acc = b_in[n];
#pragma unroll 8
    for (int e4 = 0; e4 < NEMB / 4; ++e4) {
      float4 a = er[e4];
      float4 b = wr[e4];
      acc = fmaf(a.x, b.x, acc);
      acc = fmaf(a.y, b.y, acc);
      acc = fmaf(a.z, b.z, acc);
      acc = fmaf(a.w, b.w, acc);
    }
    G[idx] = acc;
  } else if (bid < 768) {
    int n = bid - 256;                   // W_s row
    __shared__ float smax[128];
    float lw[4]; float m = 0.f;
    if (tid < 128) {
      float4 v = *(const float4*)(W_in + (size_t)n * FANIN + NEMB + tid * 4);
      lw[0] = v.x; lw[1] = v.y; lw[2] = v.z; lw[3] = v.w;
#pragma unroll
      for (int i = 0; i < 4; ++i) m = fmaxf(m, fabsf(lw[i]));
      smax[tid] = m;
    }
    __syncthreads();
    for (int s2 = 64; s2 > 0; s2 >>= 1) {
      if (tid < s2) smax[tid] = fmaxf(smax[tid], smax[tid + s2]);
      __syncthreads();
    }
    float mx = smax[0];
    if (tid < 128) {
      float r = 127.f / mx;
      uint32_t pk = 0;
#pragma unroll
      for (int i = 0; i < 4; ++i) {
        int qv = (int)rintf(lw[i] * r);
        qv = qv < -127 ? -127 : (qv > 127 ? 127 : qv);
        pk |= (uint32_t)(qv & 0xff) << (8 * i);
      }
      WqT[tid * NST + n] = (int)pk;      // sdot layout (fallback)
      int kd = tid;
      int c = kd >> 4, hi = (kd >> 2) & 3, d = kd & 3;
      int lane = hi * 16 + (n & 15), nt = n >> 4;
      WsF[(((nt * 8 + c) * 64) + lane) * 4 + d] = (int)pk;  // MFMA B-frag
    }
    if (tid == 0) Sd[n] = mx / 16129.0f;
  } else {
    int a = bid - 768;                   // W_out row
    __shared__ float smax[128];
    float lw[4]; float m = 0.f;
    if (tid < 128) {
      float4 v = *(const float4*)(W_out + (size_t)a * NST + tid * 4);
      lw[0] = v.x; lw[1] = v.y; lw[2] = v.z; lw[3] = v.w;
#pragma unroll
      for (int i = 0; i < 4; ++i) m = fmaxf(m, fabsf(lw[i]));
      smax[tid] = m;
    }
    __syncthreads();
    for (int s2 = 64; s2 > 0; s2 >>= 1) {
      if (tid < s2) smax[tid] = fmaxf(smax[tid], smax[tid + s2]);
      __syncthreads();
    }
    float mx = smax[0];
    if (tid < 128) {
      float r = 127.f / mx;
      uint32_t pk = 0;
#pragma unroll
      for (int i = 0; i < 4; ++i) {
        int qv = (int)rintf(lw[i] * r);
        qv = qv < -127 ? -127 : (qv > 127 ? 127 : qv);
        pk |= (uint32_t)(qv & 0xff) << (8 * i);
      }
      WoQ[tid * 128 + a] = (int)pk;      // fallback layout
      int kd = tid;
      int c = kd >> 4, hi = (kd >> 2) & 3, d = kd & 3;
      int lane = hi * 16 + (a & 15), ta = a >> 4;
      WoF[(((ta * 8 + c) * 64) + lane) * 4 + d] = (int)pk;  // MFMA B-frag
    }
    if (tid == 0) So[a] = mx / 16129.0f;
  }
}

// ---------------------------------------------------------------------------
// k_rec R21 — R20 engine verbatim (full-K MFMA + BAR_LDS + lane-local merge,
// 196.8 us, MfmaUtil 60%) with one micro-reorder: qs ds_write issued BEFORE
// the qrow global store, so the lgkmcnt the barrier waits on retires earlier.
// Wall model: 1306 cyc/SIMD matrix issue (structural floor — M-batching is
// S-invariant at 256 mfma/CU-step) + ~540 cyc tail.
// ---------------------------------------------------------------------------
__global__ __launch_bounds__(512, 1) void k_rec(
    const int* __restrict__ w, const float* __restrict__ G,
    const int* __restrict__ WsF, const float* __restrict__ Sd,
    signed char* __restrict__ qstates)
{
  __shared__ __align__(16) signed char qs[2][NST];
  int tid  = threadIdx.x;
  int lane = tid & 63, wv = tid >> 6;
  int l15  = lane & 15, hi = lane >> 4;
  int row  = blockIdx.x;

  // B-fragments: 4 n-tiles x 8 k-chunks (full K), 16B/lane, coalesced.
  const i32x4* wsf = (const i32x4*)WsF;
  i32x4 Bf[4][8];
#pragma unroll
  for (int q = 0; q < 4; ++q)
#pragma unroll
    for (int c = 0; c < 8; ++c)
      Bf[q][c] = wsf[((size_t)((wv * 4 + q) * 8 + c)) * 64 + lane];

  float dn = Sd[tid];
  const int* wr = w + row * TLEN;
  float g = G[wr[0] * NST + tid];

  qs[0][tid] = 0;
  __syncthreads();

  signed char* qrow = qstates + (size_t)row * TLEN * NST + tid;

  int p = 0;
  for (int t = 0; t < TLEN; ++t) {
    int tok_n = (t < TLEN - 1) ? wr[t + 1] : 0;
    float g_n = G[tok_n * NST + tid];    // prefetch; stays in flight past BAR

    // A-fragments: chunk c -> state bytes [c*64 + hi*16, +16), broadcast
    // within each 16-lane hi-group.
    i32x4 A[8];
#pragma unroll
    for (int c = 0; c < 8; ++c)
      A[c] = *(const i32x4*)(qs[p] + c * 64 + hi * 16);

    i32x4 acc0 = {0,0,0,0}, acc1 = {0,0,0,0}, acc2 = {0,0,0,0}, acc3 = {0,0,0,0};
#pragma unroll
    for (int c = 0; c < 8; ++c) {
      acc0 = __builtin_amdgcn_mfma_i32_16x16x64_i8(A[c], Bf[0][c], acc0, 0, 0, 0);
      acc1 = __builtin_amdgcn_mfma_i32_16x16x64_i8(A[c], Bf[1][c], acc1, 0, 0, 0);
      acc2 = __builtin_amdgcn_mfma_i32_16x16x64_i8(A[c], Bf[2][c], acc2, 0, 0, 0);
      acc3 = __builtin_amdgcn_mfma_i32_16x16x64_i8(A[c], Bf[3][c], acc3, 0, 0, 0);
    }

    // Merge: lane's own n = tid is tile q=hi, reg 0, col l15 (rows
    // replicated). 3-cndmask select, no cross-lane traffic (R17/R20-proven).
    int vm = (hi & 1) ? ((hi & 2) ? acc3[0] : acc1[0])
                      : ((hi & 2) ? acc2[0] : acc0[0]);

    float a = g + (float)vm * dn;
    a = fminf(fmaxf(a, -15.f), 15.f);
    float e = __expf(2.f * a);           // tanh = 1 - 2/(e^(2a)+1)
    float s = fmaf(-2.f, __builtin_amdgcn_rcpf(e + 1.f), 1.f);
    signed char q8 = (signed char)(int)rintf(s * 127.f);
    qs[p ^ 1][tid] = q8;                 // LDS first: barrier waits on this
    qrow[(size_t)t * NST] = q8;          // fire-and-forget; no vmcnt wait
    BAR_LDS();                           // fused waitcnt+barrier (race-fixed)
    g = g_n;
    p ^= 1;
  }
}

// ---------------------------------------------------------------------------
// k_out_mfma — proven in R15 (−30 us vs k_out_i8, bit-exact).
// ---------------------------------------------------------------------------
__global__ __launch_bounds__(256) void k_out_mfma(
    const signed char* __restrict__ qstates, const int* __restrict__ WoF,
    const float* __restrict__ So, const float* __restrict__ b_out,
    float* __restrict__ y)
{
  int tid = threadIdx.x;
  int lane = tid & 63, wv = tid >> 6;
  int l15 = lane & 15, hi = lane >> 4;
  size_t bt0 = (size_t)blockIdx.x * 64 + (size_t)wv * 16;

  const signed char* abase = qstates + (bt0 + l15) * NST + hi * 16;
  i32x4 A[8];
#pragma unroll
  for (int c = 0; c < 8; ++c) A[c] = *(const i32x4*)(abase + c * 64);

  const i32x4* wf = (const i32x4*)WoF;
#pragma unroll
  for (int ta = 0; ta < 8; ++ta) {
    const i32x4* bbase = wf + (size_t)ta * 8 * 64 + lane;
    i32x4 acc = {0, 0, 0, 0};
#pragma unroll
    for (int c = 0; c < 8; ++c)
      acc = __builtin_amdgcn_mfma_i32_16x16x64_i8(A[c], bbase[c * 64], acc, 0, 0, 0);
    int a = ta * 16 + l15;
    float s = So[a], b = b_out[a];
    float* yb = y + (bt0 + hi * 4) * 128 + a;
#pragma unroll
    for (int r = 0; r < 4; ++r) yb[(size_t)r * 128] = (float)acc[r] * s + b;
  }
}

// ---------------------------------------------------------------------------
// k_out_i8 — proven fallback, kept compiled for quick revert (not launched).
// ---------------------------------------------------------------------------
__global__ __launch_bounds__(256) void k_out_i8(
    const signed char* __restrict__ qstates, const int* __restrict__ WoQ,
    const float* __restrict__ So, const float* __restrict__ b_out,
    float* __restrict__ y)
{
  __shared__ __align__(16) int sl[32 * 128];   // 16 KB
  int tid = threadIdx.x;
  size_t bt0 = (size_t)blockIdx.x * 32;
  const int4* gp = (const int4*)(qstates + bt0 * NST);
  int4* slp = (int4*)sl;
#pragma unroll
  for (int i = 0; i < 4; ++i) slp[tid + 256 * i] = gp[tid + 256 * i];
  __syncthreads();

  int a0 = tid & 63, gidx = tid >> 6;
  const int* slg = sl + gidx * 8 * 128;
  int acc0[8], acc1[8];
#pragma unroll
  for (int r = 0; r < 8; ++r) { acc0[r] = 0; acc1[r] = 0; }

  for (int j4 = 0; j4 < 32; ++j4) {
    int w00 = WoQ[(4 * j4 + 0) * 128 + a0];
    int w01 = WoQ[(4 * j4 + 0) * 128 + a0 + 64];
    int w10 = WoQ[(4 * j4 + 1) * 128 + a0];
    int w11 = WoQ[(4 * j4 + 1) * 128 + a0 + 64];
    int w20 = WoQ[(4 * j4 + 2) * 128 + a0];
    int w21 = WoQ[(4 * j4 + 2) * 128 + a0 + 64];
    int w30 = WoQ[(4 * j4 + 3) * 128 + a0];
    int w31 = WoQ[(4 * j4 + 3) * 128 + a0 + 64];
#pragma unroll
    for (int r = 0; r < 8; ++r) {
      int4 s = *(const int4*)&slg[r * 128 + 4 * j4];
      acc0[r] = SDOT4(w00, s.x, acc0[r]);
      acc1[r] = SDOT4(w01, s.x, acc1[r]);
      acc0[r] = SDOT4(w10, s.y, acc0[r]);
      acc1[r] = SDOT4(w11, s.y, acc1[r]);
      acc0[r] = SDOT4(w20, s.z, acc0[r]);
      acc1[r] = SDOT4(w21, s.z, acc1[r]);
      acc0[r] = SDOT4(w30, s.w, acc0[r]);
      acc1[r] = SDOT4(w31, s.w, acc1[r]);
    }
  }

  float s0 = So[a0], s1 = So[a0 + 64];
  float b0 = b_out[a0], b1 = b_out[a0 + 64];
#pragma unroll
  for (int r = 0; r < 8; ++r) {
    size_t rowb = (bt0 + gidx * 8 + r) * 128;
    y[rowb + a0]      = (float)acc0[r] * s0 + b0;
    y[rowb + a0 + 64] = (float)acc1[r] * s1 + b1;
  }
}

// ---------------------------------------------------------------------------
extern "C" void kernel_launch(void* const* d_in, const int* in_sizes, int n_in,
                              void* d_out, int out_size, void* d_ws, size_t ws_size,
                              hipStream_t stream) {
  const int*   w     = (const int*)d_in[0];
  const float* emb   = (const float*)d_in[1];
  const float* W_in  = (const float*)d_in[2];
  const float* b_in  = (const float*)d_in[3];
  const float* W_out = (const float*)d_in[4];
  const float* b_out = (const float*)d_in[5];
  float* y = (float*)d_out;

  // Workspace map (R16 lesson: WoF is 64 KB — 128 rows x 512 B):
  //   [0,256K)     G
  //   [256K,512K)  WqT
  //   [512K,514K)  Sd
  //   [576K,640K)  WoQ   (64 KB)
  //   [640K,641K)  So
  //   [704K,768K)  WoF   (64 KB, frag-order)
  //   [768K,1024K) WsF   (256 KB, frag-order) — ends exactly at qstates
  //   [1024K,+32M) qstates
  char* ws = (char*)d_ws;
  float*       G       = (float*)ws;
  int*         WqT     = (int*)(ws + (256 << 10));
  float*       Sd      = (float*)(ws + (512 << 10));
  int*         WoQ     = (int*)(ws + (576 << 10));
  float*       So      = (float*)(ws + (640 << 10));
  int*         WoF     = (int*)(ws + (704 << 10));
  int*         WsF     = (int*)(ws + (768 << 10));
  signed char* qstates = (signed char*)(ws + (1024 << 10));

  k_prep<<<896, 256, 0, stream>>>(emb, W_in, b_in, W_out, G, WqT, Sd, WoQ, WoF, So, WsF);
  k_rec <<<BATCH, 512, 0, stream>>>(w, G, WsF, Sd, qstates);
  k_out_mfma<<<BATCH * TLEN / 64, 256, 0, stream>>>(qstates, WoF, So, b_out, y);
}